// Round 3
// baseline (286.368 us; speedup 1.0000x reference)
//
#include <hip/hip_runtime.h>

#define STEPS 30
#define HID 32
#define TPB 256
#define LDS_STRIDE (STEPS + 1)   // 31: odd stride -> conflict-free column access

// Pin a value into a VGPR: opaque to the compiler, cannot be rematerialized
// by re-issuing the global load inside the loop (the R1/R2 failure mode).
#define PIN(x) asm volatile("" : "+v"(x))

__global__ __launch_bounds__(TPB, 2) void hedge_kernel(
    const float* __restrict__ S,
    const float* __restrict__ W1,
    const float* __restrict__ b1,
    const float* __restrict__ W2,
    const float* __restrict__ b2,
    const float* __restrict__ a_init,
    float* __restrict__ out)
{
    __shared__ float tile[TPB * LDS_STRIDE];   // 256*31*4 = 31744 B
    const int tid = threadIdx.x;
    const long long base = (long long)blockIdx.x * (TPB * STEPS);

    // ---- Stage S tile (256 elems x 30 steps) coalesced into padded LDS ----
    const float2* __restrict__ S2 = (const float2*)(S + base);
    #pragma unroll
    for (int k = 0; k < (TPB * STEPS) / (2 * TPB); ++k) {   // 15 iters
        int g2 = tid + k * TPB;
        float2 v = S2[g2];
        int g = g2 * 2;
        int row = g / STEPS;
        int col = g - row * STEPS;
        tile[row * LDS_STRIDE + col]     = v.x;
        tile[row * LDS_STRIDE + col + 1] = v.y;
    }

    // ---- All 160 weights into pinned VGPRs ----
    float wa[HID], wc[HID], we[HID], wb[HID], w2[HID];
    #pragma unroll
    for (int q = 0; q < HID / 4; ++q) {
        float4 va = ((const float4*)(W1 + 0 * HID))[q];  // coeff of s
        float4 vc = ((const float4*)(W1 + 1 * HID))[q];  // coeff of d_prev
        float4 ve = ((const float4*)(W1 + 2 * HID))[q];  // coeff of h
        float4 vb = ((const float4*)b1)[q];
        float4 v2 = ((const float4*)W2)[q];
        wa[4*q+0]=va.x; wa[4*q+1]=va.y; wa[4*q+2]=va.z; wa[4*q+3]=va.w;
        wc[4*q+0]=vc.x; wc[4*q+1]=vc.y; wc[4*q+2]=vc.z; wc[4*q+3]=vc.w;
        we[4*q+0]=ve.x; we[4*q+1]=ve.y; we[4*q+2]=ve.z; we[4*q+3]=ve.w;
        wb[4*q+0]=vb.x; wb[4*q+1]=vb.y; wb[4*q+2]=vb.z; wb[4*q+3]=vb.w;
        w2[4*q+0]=v2.x; w2[4*q+1]=v2.y; w2[4*q+2]=v2.z; w2[4*q+3]=v2.w;
    }
    #pragma unroll
    for (int j = 0; j < HID; ++j) {
        PIN(wa[j]); PIN(wc[j]); PIN(we[j]); PIN(wb[j]); PIN(w2[j]);
    }
    const float bias2 = b2[0];
    float d = a_init[0];
    float h = 0.0f;
    __syncthreads();

    // ---- Recurrence: one thread = one element; no cross-lane ops on the chain ----
    float* my = &tile[tid * LDS_STRIDE];
    #pragma unroll 2   // body ~360 instr ≈ 2.5 KB: I-cache safe, still overlaps steps
    for (int t = 0; t < STEPS; ++t) {
        const float s = my[t];   // off-chain LDS read, prefetchable
        // 8 accumulators: 4-deep FMA chains + 3-level tree keeps latency ~30 cyc
        float acc[8];
        #pragma unroll
        for (int g = 0; g < 8; ++g) acc[g] = 0.0f;
        #pragma unroll
        for (int j = 0; j < HID; ++j) {
            // sp is recurrence-independent: compiler can issue next step's sp
            // during this step's reduction tree.
            float sp = fmaf(wa[j], s, wb[j]);
            float tj = fmaf(wc[j], d, sp);
            tj = fmaf(we[j], h, tj);
            acc[j & 7] = fmaf(fmaxf(tj, 0.0f), w2[j], acc[j & 7]);
        }
        float s01 = acc[0] + acc[1], s23 = acc[2] + acc[3];
        float s45 = acc[4] + acc[5], s67 = acc[6] + acc[7];
        const float dn = bias2 + ((s01 + s23) + (s45 + s67));
        h = fmaf(0.2f, dn, 0.8f * h);
        d = dn;
        my[t] = dn;              // S[t] consumed; slot reused for output d_t
    }
    __syncthreads();

    // ---- Dump outputs coalesced (same flat layout as S) ----
    float2* __restrict__ O2 = (float2*)(out + base);
    #pragma unroll
    for (int k = 0; k < (TPB * STEPS) / (2 * TPB); ++k) {   // 15 iters
        int g2 = tid + k * TPB;
        int g = g2 * 2;
        int row = g / STEPS;
        int col = g - row * STEPS;
        float2 v;
        v.x = tile[row * LDS_STRIDE + col];
        v.y = tile[row * LDS_STRIDE + col + 1];
        O2[g2] = v;
    }
}

extern "C" void kernel_launch(void* const* d_in, const int* in_sizes, int n_in,
                              void* d_out, int out_size, void* d_ws, size_t ws_size,
                              hipStream_t stream) {
    const float* S      = (const float*)d_in[0];
    const float* W1     = (const float*)d_in[1];
    const float* b1     = (const float*)d_in[2];
    const float* W2     = (const float*)d_in[3];
    const float* b2     = (const float*)d_in[4];
    const float* a_init = (const float*)d_in[5];
    float* out = (float*)d_out;

    const int batch = in_sizes[0] / STEPS;    // 1048576
    const int grid  = batch / TPB;            // 4096
    hedge_kernel<<<grid, TPB, 0, stream>>>(S, W1, b1, W2, b2, a_init, out);
}